// Round 7
// baseline (614.948 us; speedup 1.0000x reference)
//
#include <hip/hip_runtime.h>
#include <math.h>

#define Wd 256
#define Hd 256
#define KW 11
#define OUT_R 16              // output rows per block (band)
#define NPAIR 13              // 26 streamed rows = OUT_R + 10
#define BLOCK 256

typedef float v2f __attribute__((ext_vector_type(2)));

__device__ __forceinline__ float rfl(float v) {
    return __int_as_float(__builtin_amdgcn_readfirstlane(__float_as_int(v)));
}

// Vertical-first SSIM, row-pair rounds. Thread = one column of a 16-row band.
// Raw rows stream from global (coalesced b32, no input LDS). Vertical 11-tap
// conv runs in a 4-channel register ring (26 rows fully unrolled -> all slot
// indices static). Each round: vertical conv for TWO rows -> double-buffered
// LDS row buffers (even/odd column split, lane-contiguous b128) -> ONE barrier
// -> horizontal pass with ALL 256 lanes (waves 0-1: row 0, waves 2-3: row 1),
// 2 adjacent output columns per thread (12 ds_read_b128 per 2x2 outputs).
// Zero conv padding: invalid rows carry zero ring slots; column halos zeroed once.
__global__ __launch_bounds__(BLOCK, 5) void ssim_stream_kernel(
    const float* __restrict__ img1, const float* __restrict__ img2,
    const float* __restrict__ window, float* __restrict__ out, float scale)
{
    // rbE[buf][row][e+2] holds col 2e  (e=-2..130 -> idx 0..132)
    // rbO[buf][row][o+3] holds col 2o+1 (o=-3..129 -> idx 0..132)
    __shared__ __align__(16) float4 rbE[2][2][136];
    __shared__ __align__(16) float4 rbO[2][2][136];   // 2*2*2*136*16 = 17.4 KB
    __shared__ float red[BLOCK / 64];

    const float C1 = 1e-4f, C2 = 9e-4f;
    const int t = threadIdx.x;
    const int band = blockIdx.x;     // 0..15
    const int plane = blockIdx.y;    // 0..143
    const float* __restrict__ p1 = img1 + (size_t)plane * (Hd * Wd);
    const float* __restrict__ p2 = img2 + (size_t)plane * (Hd * Wd);

    // Separable 1D weights (win2d = a outer a, sum a = 1); pin to SGPRs.
    float wl[KW];
    {
        float c = sqrtf(window[5 * KW + 5]);
        #pragma unroll
        for (int k = 0; k < KW; ++k)
            wl[k] = rfl(window[k * KW + 5] / c);
    }

    // Zero the column-halo cells once (never written by the row pass).
    if (t < 4) {
        int buf = t >> 1, row = t & 1;
        float4 z = make_float4(0.f, 0.f, 0.f, 0.f);
        rbE[buf][row][0] = z; rbE[buf][row][1] = z;
        rbE[buf][row][130] = z; rbE[buf][row][131] = z; rbE[buf][row][132] = z;
        rbO[buf][row][0] = z; rbO[buf][row][1] = z; rbO[buf][row][2] = z;
        rbO[buf][row][131] = z; rbO[buf][row][132] = z;
    }

    const int ghbase = band * OUT_R - 5;   // global row of stream index 0

    v2f rXY[KW], rQP[KW];
    float acc = 0.f;

    float x0, y0, x1, y1;
    {
        int g0 = ghbase, g1 = ghbase + 1;
        x0 = ((unsigned)g0 < (unsigned)Hd) ? p1[(g0 << 8) + t] : 0.f;
        y0 = ((unsigned)g0 < (unsigned)Hd) ? p2[(g0 << 8) + t] : 0.f;
        x1 = ((unsigned)g1 < (unsigned)Hd) ? p1[(g1 << 8) + t] : 0.f;
        y1 = ((unsigned)g1 < (unsigned)Hd) ? p2[(g1 << 8) + t] : 0.f;
    }

    #pragma unroll
    for (int p = 0; p < NPAIR; ++p) {
        // ring insert rows 2p, 2p+1 (invalid rows carry zeros -> zero padding)
        {
            const int s0 = (2 * p) % KW, s1 = (2 * p + 1) % KW;
            v2f v; v.x = x0; v.y = y0; rXY[s0] = v;
            v2f q; q.x = fmaf(x0, x0, y0 * y0); q.y = x0 * y0; rQP[s0] = q;
            v2f v2; v2.x = x1; v2.y = y1; rXY[s1] = v2;
            v2f q2; q2.x = fmaf(x1, x1, y1 * y1); q2.y = x1 * y1; rQP[s1] = q2;
        }
        // prefetch next pair (consumed next iteration)
        if (p + 1 < NPAIR) {
            int g0 = ghbase + 2 * p + 2, g1 = ghbase + 2 * p + 3;
            x0 = ((unsigned)g0 < (unsigned)Hd) ? p1[(g0 << 8) + t] : 0.f;
            y0 = ((unsigned)g0 < (unsigned)Hd) ? p2[(g0 << 8) + t] : 0.f;
            x1 = ((unsigned)g1 < (unsigned)Hd) ? p1[(g1 << 8) + t] : 0.f;
            y1 = ((unsigned)g1 < (unsigned)Hd) ? p2[(g1 << 8) + t] : 0.f;
        }

        if (p >= 5) {                       // emit rows 2p, 2p+1 (stream idx 10..25)
            const int buf = p & 1;
            // vertical 11-tap conv, rows 2p (slots (2p+1+m)%11) and 2p+1
            v2f vAB0, vQP0, vAB1, vQP1;
            vAB0.x = vAB0.y = vQP0.x = vQP0.y = 0.f;
            vAB1.x = vAB1.y = vQP1.x = vQP1.y = 0.f;
            #pragma unroll
            for (int m = 0; m < KW; ++m) {
                const int sa = (2 * p + 1 + m) % KW;   // static
                const int sb = (2 * p + 2 + m) % KW;   // static
                float w = wl[m];
                vAB0 += w * rXY[sa];  vQP0 += w * rQP[sa];
                vAB1 += w * rXY[sb];  vQP1 += w * rQP[sb];
            }
            const int half = t >> 1;
            if (t & 1) {
                rbO[buf][0][half + 3] = make_float4(vAB0.x, vAB0.y, vQP0.x, vQP0.y);
                rbO[buf][1][half + 3] = make_float4(vAB1.x, vAB1.y, vQP1.x, vQP1.y);
            } else {
                rbE[buf][0][half + 2] = make_float4(vAB0.x, vAB0.y, vQP0.x, vQP0.y);
                rbE[buf][1][half + 2] = make_float4(vAB1.x, vAB1.y, vQP1.x, vQP1.y);
            }
            __syncthreads();

            // horizontal: all lanes busy. waves 0-1 -> row 0, waves 2-3 -> row 1
            const int r = t >> 7, cp = t & 127;        // output cols 2cp, 2cp+1
            const float4* bE = &rbE[buf][r][cp];
            const float4* bO = &rbO[buf][r][cp];
            v2f a0, q0, a1, q1;
            a0.x = a0.y = q0.x = q0.y = 0.f;
            a1.x = a1.y = q1.x = q1.y = 0.f;
            #pragma unroll
            for (int k = 0; k < 6; ++k) {
                float4 vO = bO[k];                     // ds_read_b128
                v2f oab; oab.x = vO.x; oab.y = vO.y;
                v2f oqp; oqp.x = vO.z; oqp.y = vO.w;
                a0 += wl[2 * k] * oab;  q0 += wl[2 * k] * oqp;
                if (k >= 1) { a1 += wl[2 * k - 1] * oab;  q1 += wl[2 * k - 1] * oqp; }
                float4 vE = bE[k];                     // ds_read_b128
                v2f eab; eab.x = vE.x; eab.y = vE.y;
                v2f eqp; eqp.x = vE.z; eqp.y = vE.w;
                a1 += wl[2 * k] * eab;  q1 += wl[2 * k] * eqp;
                if (k <= 4) { a0 += wl[2 * k + 1] * eab;  q0 += wl[2 * k + 1] * eqp; }
            }
            {
                float mu1 = a0.x, mu2 = a0.y, sq = q0.x, sp = q0.y;
                float mu1sq = mu1 * mu1, mu2sq = mu2 * mu2, mu12 = mu1 * mu2;
                float musum = mu1sq + mu2sq;
                float num = (2.f * mu12 + C1) * (2.f * (sp - mu12) + C2);
                float den = (musum + C1) * ((sq - musum) + C2);
                acc += num * __builtin_amdgcn_rcpf(den);
            }
            {
                float mu1 = a1.x, mu2 = a1.y, sq = q1.x, sp = q1.y;
                float mu1sq = mu1 * mu1, mu2sq = mu2 * mu2, mu12 = mu1 * mu2;
                float musum = mu1sq + mu2sq;
                float num = (2.f * mu12 + C1) * (2.f * (sp - mu12) + C2);
                float den = (musum + C1) * ((sq - musum) + C2);
                acc += num * __builtin_amdgcn_rcpf(den);
            }
        }
    }

    // --- block reduction + fused global reduce (atomic) ---
    #pragma unroll
    for (int off = 32; off > 0; off >>= 1)
        acc += __shfl_down(acc, off, 64);
    int wave = t >> 6;
    if ((t & 63) == 0) red[wave] = acc;
    __syncthreads();
    if (t == 0) {
        float partial = red[0] + red[1] + red[2] + red[3];
        float v = partial * scale;                 // scale = -1/count
        if (band == 0 && plane == 0) v += 1.0f;    // out = 1 - sum/count
        atomicAdd(out, v);
    }
}

extern "C" void kernel_launch(void* const* d_in, const int* in_sizes, int n_in,
                              void* d_out, int out_size, void* d_ws, size_t ws_size,
                              hipStream_t stream) {
    const float* img1   = (const float*)d_in[0];
    const float* img2   = (const float*)d_in[1];
    const float* window = (const float*)d_in[2];
    float* out = (float*)d_out;

    const int planes = 16 * 9;            // 144
    const int bands = Hd / OUT_R;         // 16

    hipMemsetAsync(out, 0, sizeof(float), stream);

    const float scale = -(float)(1.0 / ((double)planes * Hd * Wd));
    dim3 grid(bands, planes);
    ssim_stream_kernel<<<grid, BLOCK, 0, stream>>>(img1, img2, window, out, scale);
}

// Round 8
// 264.910 us; speedup vs baseline: 2.3213x; 2.3213x over previous
//
#include <hip/hip_runtime.h>
#include <math.h>

#define Wd 256
#define Hd 256
#define KW 11
#define OUT_R 16              // output rows per block (band)
#define BLOCK 256

typedef float v2f __attribute__((ext_vector_type(2)));

__device__ __forceinline__ float rfl(float v) {
    return __int_as_float(__builtin_amdgcn_readfirstlane(__float_as_int(v)));
}

// Vertical-first SSIM, row-pair rounds, STRAIGHT-LINE 13-step stream.
// R7 post-mortem: a 13-iter loop with "#pragma unroll" did NOT unroll ->
// ring %11 indices went dynamic -> rXY/rQP demoted to scratch (714 MB of
// scratch writes). Here each step is macro-expanded with a literal P, so
// every ring slot (2P+c)%11 is a compile-time constant structurally.
//
// Thread = one column of a 16-row band. Raw rows stream from global
// (coalesced b32, no input LDS). Vertical 11-tap conv in a 4-channel
// register ring. Per emit step: vertical conv for TWO rows -> double-
// buffered LDS row buffers (even/odd column split, lane-contiguous b128)
// -> ONE barrier -> horizontal pass with ALL 256 lanes (waves 0-1: row 0,
// waves 2-3: row 1), 2 adjacent output columns per thread.
__global__ __launch_bounds__(BLOCK, 4) void ssim_stream_kernel(
    const float* __restrict__ img1, const float* __restrict__ img2,
    const float* __restrict__ window, float* __restrict__ out, float scale)
{
    // rbE[buf][row][e+2] holds col 2e  (e=-2..130 -> idx 0..132)
    // rbO[buf][row][o+3] holds col 2o+1 (o=-3..129 -> idx 0..132)
    __shared__ __align__(16) float4 rbE[2][2][136];
    __shared__ __align__(16) float4 rbO[2][2][136];   // 17.4 KB
    __shared__ float red[BLOCK / 64];

    const float C1 = 1e-4f, C2 = 9e-4f;
    const int t = threadIdx.x;
    const int band = blockIdx.x;     // 0..15
    const int plane = blockIdx.y;    // 0..143
    const float* __restrict__ p1 = img1 + (size_t)plane * (Hd * Wd);
    const float* __restrict__ p2 = img2 + (size_t)plane * (Hd * Wd);

    // Separable 1D weights (win2d = a outer a, sum a = 1); pin to SGPRs.
    float wl[KW];
    {
        float c = sqrtf(window[5 * KW + 5]);
        #pragma unroll
        for (int k = 0; k < KW; ++k)
            wl[k] = rfl(window[k * KW + 5] / c);
    }

    // Zero the column-halo cells once (never written by the row pass).
    if (t < 4) {
        int buf = t >> 1, row = t & 1;
        float4 z = make_float4(0.f, 0.f, 0.f, 0.f);
        rbE[buf][row][0] = z; rbE[buf][row][1] = z;
        rbE[buf][row][130] = z; rbE[buf][row][131] = z; rbE[buf][row][132] = z;
        rbO[buf][row][0] = z; rbO[buf][row][1] = z; rbO[buf][row][2] = z;
        rbO[buf][row][131] = z; rbO[buf][row][132] = z;
    }
    // (first barrier inside STEP(5) makes these visible before any read)

    const int ghbase = band * OUT_R - 5;   // global row of stream index 0

    v2f rXY[KW], rQP[KW];
    float acc = 0.f;

    float px0, py0, px1, py1;   // current pair (rows 2P, 2P+1)
    {
        int g0 = ghbase, g1 = ghbase + 1;
        px0 = ((unsigned)g0 < (unsigned)Hd) ? p1[(g0 << 8) + t] : 0.f;
        py0 = ((unsigned)g0 < (unsigned)Hd) ? p2[(g0 << 8) + t] : 0.f;
        px1 = ((unsigned)g1 < (unsigned)Hd) ? p1[(g1 << 8) + t] : 0.f;
        py1 = ((unsigned)g1 < (unsigned)Hd) ? p2[(g1 << 8) + t] : 0.f;
    }

#define INSERT0(P) { \
    v2f v; v.x = px0; v.y = py0; rXY[(2*(P)) % KW] = v; \
    v2f q; q.x = fmaf(px0, px0, py0 * py0); q.y = px0 * py0; rQP[(2*(P)) % KW] = q; }

#define INSERT1(P) { \
    v2f v; v.x = px1; v.y = py1; rXY[(2*(P)+1) % KW] = v; \
    v2f q; q.x = fmaf(px1, px1, py1 * py1); q.y = px1 * py1; rQP[(2*(P)+1) % KW] = q; }

#define PREFETCH(P) if ((P) < 12) { \
    int g0 = ghbase + 2*(P) + 2, g1 = ghbase + 2*(P) + 3; \
    px0 = ((unsigned)g0 < (unsigned)Hd) ? p1[(g0 << 8) + t] : 0.f; \
    py0 = ((unsigned)g0 < (unsigned)Hd) ? p2[(g0 << 8) + t] : 0.f; \
    px1 = ((unsigned)g1 < (unsigned)Hd) ? p1[(g1 << 8) + t] : 0.f; \
    py1 = ((unsigned)g1 < (unsigned)Hd) ? p2[(g1 << 8) + t] : 0.f; }

#define VERT(P, OFS, vAB, vQP) { \
    vAB.x = vAB.y = vQP.x = vQP.y = 0.f; \
    _Pragma("unroll") \
    for (int m = 0; m < KW; ++m) { \
        const int s = (2*(P) + (OFS) + m) % KW;  /* constant: P literal */ \
        float w = wl[m]; \
        vAB += w * rXY[s]; \
        vQP += w * rQP[s]; \
    } }

#define EPILOGUE(a, q) { \
    float mu1 = a.x, mu2 = a.y, sq = q.x, sp = q.y; \
    float mu1sq = mu1 * mu1, mu2sq = mu2 * mu2, mu12 = mu1 * mu2; \
    float musum = mu1sq + mu2sq; \
    float num = (2.f * mu12 + C1) * (2.f * (sp - mu12) + C2); \
    float den = (musum + C1) * ((sq - musum) + C2); \
    acc += num * __builtin_amdgcn_rcpf(den); }

#define STEP_WARM(P) { INSERT0(P) INSERT1(P) PREFETCH(P) }

#define STEP_EMIT(P) { \
    const int buf = (P) & 1; \
    v2f vAB0, vQP0, vAB1, vQP1; \
    INSERT0(P) \
    VERT(P, 1, vAB0, vQP0)            /* row 2P: slots (2P+1+m)%11 */ \
    INSERT1(P) \
    VERT(P, 2, vAB1, vQP1)            /* row 2P+1: slots (2P+2+m)%11 */ \
    PREFETCH(P) \
    { \
        const int half = t >> 1; \
        if (t & 1) { \
            rbO[buf][0][half + 3] = make_float4(vAB0.x, vAB0.y, vQP0.x, vQP0.y); \
            rbO[buf][1][half + 3] = make_float4(vAB1.x, vAB1.y, vQP1.x, vQP1.y); \
        } else { \
            rbE[buf][0][half + 2] = make_float4(vAB0.x, vAB0.y, vQP0.x, vQP0.y); \
            rbE[buf][1][half + 2] = make_float4(vAB1.x, vAB1.y, vQP1.x, vQP1.y); \
        } \
    } \
    __syncthreads(); \
    { \
        const int r = t >> 7, cp = t & 127;    /* output cols 2cp, 2cp+1 */ \
        const float4* bE = &rbE[buf][r][cp]; \
        const float4* bO = &rbO[buf][r][cp]; \
        v2f a0, q0, a1, q1; \
        a0.x = a0.y = q0.x = q0.y = 0.f; \
        a1.x = a1.y = q1.x = q1.y = 0.f; \
        _Pragma("unroll") \
        for (int k = 0; k < 6; ++k) { \
            float4 vO = bO[k];                 /* ds_read_b128 */ \
            v2f oab; oab.x = vO.x; oab.y = vO.y; \
            v2f oqp; oqp.x = vO.z; oqp.y = vO.w; \
            a0 += wl[2 * k] * oab;  q0 += wl[2 * k] * oqp; \
            if (k >= 1) { a1 += wl[2 * k - 1] * oab;  q1 += wl[2 * k - 1] * oqp; } \
            float4 vE = bE[k];                 /* ds_read_b128 */ \
            v2f eab; eab.x = vE.x; eab.y = vE.y; \
            v2f eqp; eqp.x = vE.z; eqp.y = vE.w; \
            a1 += wl[2 * k] * eab;  q1 += wl[2 * k] * eqp; \
            if (k <= 4) { a0 += wl[2 * k + 1] * eab;  q0 += wl[2 * k + 1] * eqp; } \
        } \
        EPILOGUE(a0, q0) \
        EPILOGUE(a1, q1) \
    } }

    // 13 straight-line steps: rows 0..25 streamed, rows 10..25 emitted.
    STEP_WARM(0) STEP_WARM(1) STEP_WARM(2) STEP_WARM(3) STEP_WARM(4)
    STEP_EMIT(5) STEP_EMIT(6) STEP_EMIT(7) STEP_EMIT(8)
    STEP_EMIT(9) STEP_EMIT(10) STEP_EMIT(11) STEP_EMIT(12)

#undef STEP_EMIT
#undef STEP_WARM
#undef EPILOGUE
#undef VERT
#undef PREFETCH
#undef INSERT1
#undef INSERT0

    // --- block reduction + fused global reduce (atomic) ---
    #pragma unroll
    for (int off = 32; off > 0; off >>= 1)
        acc += __shfl_down(acc, off, 64);
    int wave = t >> 6;
    if ((t & 63) == 0) red[wave] = acc;
    __syncthreads();
    if (t == 0) {
        float partial = red[0] + red[1] + red[2] + red[3];
        float v = partial * scale;                 // scale = -1/count
        if (band == 0 && plane == 0) v += 1.0f;    // out = 1 - sum/count
        atomicAdd(out, v);
    }
}

extern "C" void kernel_launch(void* const* d_in, const int* in_sizes, int n_in,
                              void* d_out, int out_size, void* d_ws, size_t ws_size,
                              hipStream_t stream) {
    const float* img1   = (const float*)d_in[0];
    const float* img2   = (const float*)d_in[1];
    const float* window = (const float*)d_in[2];
    float* out = (float*)d_out;

    const int planes = 16 * 9;            // 144
    const int bands = Hd / OUT_R;         // 16

    hipMemsetAsync(out, 0, sizeof(float), stream);

    const float scale = -(float)(1.0 / ((double)planes * Hd * Wd));
    dim3 grid(bands, planes);
    ssim_stream_kernel<<<grid, BLOCK, 0, stream>>>(img1, img2, window, out, scale);
}

// Round 9
// 123.730 us; speedup vs baseline: 4.9701x; 2.1410x over previous
//
#include <hip/hip_runtime.h>
#include <math.h>

#define Wd 256
#define Hd 256
#define KW 11
#define OUT_R 26              // output rows per block; stream 36 = 3 chunks of 12
#define RING 12               // ring size 12: slot=(2*jp+c)%12, chunk-independent
#define BLOCK 256

typedef float v2f __attribute__((ext_vector_type(2)));

__device__ __forceinline__ float rfl(float v) {
    return __int_as_float(__builtin_amdgcn_readfirstlane(__float_as_int(v)));
}

// Vertical-first SSIM, row-pair rounds inside the R6-proven loop shape
// (outer runtime chunk loop `#pragma unroll 1`, inner fully-unrolled steps —
// the only structure measured to hold the 44-float ring without scratch;
// R7/R8 straight-line variants spilled 238-714 MB).
//
// Ring of 12: stream row i = 12*ch + 2*jp + c  ->  slot (2*jp+c)%12, static
// and independent of ch. Per pair-step: insert 2 rows, vertical 11-tap conv
// for both (register ring, static slots), results -> double-buffered LDS
// row buffers (even/odd column split, lane-contiguous b128), ONE barrier,
// horizontal 11-tap with ALL 256 lanes (waves 0-1: row 0, waves 2-3: row 1),
// 2 adjacent output columns per thread. Zero conv padding via zero ring rows
// and zeroed column halos.
__global__ __launch_bounds__(BLOCK, 4) void ssim_pair_kernel(
    const float* __restrict__ img1, const float* __restrict__ img2,
    const float* __restrict__ window, float* __restrict__ out, float scale)
{
    // rbE[buf][row][e+2] holds col 2e  (e=-2..130 -> idx 0..132)
    // rbO[buf][row][o+3] holds col 2o+1 (o=-3..129 -> idx 0..132)
    __shared__ __align__(16) float4 rbE[2][2][136];
    __shared__ __align__(16) float4 rbO[2][2][136];   // 17.4 KB
    __shared__ float red[BLOCK / 64];

    const float C1 = 1e-4f, C2 = 9e-4f;
    const int t = threadIdx.x;
    const int band = blockIdx.x;     // 0..9 (band 9 partial: 22 rows)
    const int plane = blockIdx.y;    // 0..143
    const float* __restrict__ p1 = img1 + (size_t)plane * (Hd * Wd);
    const float* __restrict__ p2 = img2 + (size_t)plane * (Hd * Wd);

    // Separable 1D weights (win2d = a outer a, sum a = 1); pin to SGPRs.
    float wl[KW];
    {
        float c = sqrtf(window[5 * KW + 5]);
        #pragma unroll
        for (int k = 0; k < KW; ++k)
            wl[k] = rfl(window[k * KW + 5] / c);
    }

    // Zero the column-halo cells once (never written by the row pass);
    // visible to readers via the first emit-step barrier.
    if (t < 4) {
        int buf = t >> 1, row = t & 1;
        float4 z = make_float4(0.f, 0.f, 0.f, 0.f);
        rbE[buf][row][0] = z; rbE[buf][row][1] = z;
        rbE[buf][row][130] = z; rbE[buf][row][131] = z; rbE[buf][row][132] = z;
        rbO[buf][row][0] = z; rbO[buf][row][1] = z; rbO[buf][row][2] = z;
        rbO[buf][row][131] = z; rbO[buf][row][132] = z;
    }

    const int ghbase = band * OUT_R - 5;   // global row of stream index 0

    v2f rXY[RING], rQP[RING];
    float acc = 0.f;

    float px0, py0, px1, py1;   // current pair (stream rows i0, i0+1)
    {
        int g0 = ghbase, g1 = ghbase + 1;
        px0 = ((unsigned)g0 < (unsigned)Hd) ? p1[(g0 << 8) + t] : 0.f;
        py0 = ((unsigned)g0 < (unsigned)Hd) ? p2[(g0 << 8) + t] : 0.f;
        px1 = ((unsigned)g1 < (unsigned)Hd) ? p1[(g1 << 8) + t] : 0.f;
        py1 = ((unsigned)g1 < (unsigned)Hd) ? p2[(g1 << 8) + t] : 0.f;
    }

    #pragma unroll 1
    for (int ch = 0; ch < 3; ++ch) {
        #pragma unroll
        for (int jp = 0; jp < 6; ++jp) {
            const int i0 = 12 * ch + 2 * jp;        // uniform (ch runtime)
            const int s0 = (2 * jp) % RING;         // STATIC slot
            const int s1 = (2 * jp + 1) % RING;     // STATIC slot

            // ring insert rows i0, i0+1 (out-of-range rows carry zeros)
            {
                v2f v; v.x = px0; v.y = py0; rXY[s0] = v;
                v2f q; q.x = fmaf(px0, px0, py0 * py0); q.y = px0 * py0; rQP[s0] = q;
                v2f v2; v2.x = px1; v2.y = py1; rXY[s1] = v2;
                v2f q2; q2.x = fmaf(px1, px1, py1 * py1); q2.y = px1 * py1; rQP[s1] = q2;
            }
            // prefetch next pair (consumed next step)
            if (i0 + 2 < 36) {
                int g0 = ghbase + i0 + 2, g1 = ghbase + i0 + 3;
                px0 = ((unsigned)g0 < (unsigned)Hd) ? p1[(g0 << 8) + t] : 0.f;
                py0 = ((unsigned)g0 < (unsigned)Hd) ? p2[(g0 << 8) + t] : 0.f;
                px1 = ((unsigned)g1 < (unsigned)Hd) ? p1[(g1 << 8) + t] : 0.f;
                py1 = ((unsigned)g1 < (unsigned)Hd) ? p2[(g1 << 8) + t] : 0.f;
            }

            const int orow0 = band * OUT_R + i0 - 10;     // uniform
            if (i0 >= 10 && orow0 < Hd) {   // emit rows i0, i0+1
                const int buf = jp & 1;     // alternates across emit sequence
                // vertical 11-tap conv: row i0 slots (2jp+2+m)%12,
                //                       row i0+1 slots (2jp+3+m)%12 — STATIC
                v2f vAB0, vQP0, vAB1, vQP1;
                vAB0.x = vAB0.y = vQP0.x = vQP0.y = 0.f;
                vAB1.x = vAB1.y = vQP1.x = vQP1.y = 0.f;
                #pragma unroll
                for (int m = 0; m < KW; ++m) {
                    const int sa = (2 * jp + 2 + m) % RING;
                    const int sb = (2 * jp + 3 + m) % RING;
                    float w = wl[m];
                    vAB0 += w * rXY[sa];  vQP0 += w * rQP[sa];
                    vAB1 += w * rXY[sb];  vQP1 += w * rQP[sb];
                }
                const int half = t >> 1;
                if (t & 1) {
                    rbO[buf][0][half + 3] = make_float4(vAB0.x, vAB0.y, vQP0.x, vQP0.y);
                    rbO[buf][1][half + 3] = make_float4(vAB1.x, vAB1.y, vQP1.x, vQP1.y);
                } else {
                    rbE[buf][0][half + 2] = make_float4(vAB0.x, vAB0.y, vQP0.x, vQP0.y);
                    rbE[buf][1][half + 2] = make_float4(vAB1.x, vAB1.y, vQP1.x, vQP1.y);
                }
                __syncthreads();

                // horizontal: all 256 lanes. waves 0-1 -> row 0, 2-3 -> row 1
                const int r = t >> 7, cp = t & 127;   // output cols 2cp, 2cp+1
                const float4* bE = &rbE[buf][r][cp];
                const float4* bO = &rbO[buf][r][cp];
                v2f a0, q0, a1, q1;
                a0.x = a0.y = q0.x = q0.y = 0.f;
                a1.x = a1.y = q1.x = q1.y = 0.f;
                #pragma unroll
                for (int k = 0; k < 6; ++k) {
                    float4 vO = bO[k];                 // ds_read_b128
                    v2f oab; oab.x = vO.x; oab.y = vO.y;
                    v2f oqp; oqp.x = vO.z; oqp.y = vO.w;
                    a0 += wl[2 * k] * oab;  q0 += wl[2 * k] * oqp;
                    if (k >= 1) { a1 += wl[2 * k - 1] * oab;  q1 += wl[2 * k - 1] * oqp; }
                    float4 vE = bE[k];                 // ds_read_b128
                    v2f eab; eab.x = vE.x; eab.y = vE.y;
                    v2f eqp; eqp.x = vE.z; eqp.y = vE.w;
                    a1 += wl[2 * k] * eab;  q1 += wl[2 * k] * eqp;
                    if (k <= 4) { a0 += wl[2 * k + 1] * eab;  q0 += wl[2 * k + 1] * eqp; }
                }
                {
                    float mu1 = a0.x, mu2 = a0.y, sq = q0.x, sp = q0.y;
                    float mu1sq = mu1 * mu1, mu2sq = mu2 * mu2, mu12 = mu1 * mu2;
                    float musum = mu1sq + mu2sq;
                    float num = (2.f * mu12 + C1) * (2.f * (sp - mu12) + C2);
                    float den = (musum + C1) * ((sq - musum) + C2);
                    acc += num * __builtin_amdgcn_rcpf(den);
                }
                {
                    float mu1 = a1.x, mu2 = a1.y, sq = q1.x, sp = q1.y;
                    float mu1sq = mu1 * mu1, mu2sq = mu2 * mu2, mu12 = mu1 * mu2;
                    float musum = mu1sq + mu2sq;
                    float num = (2.f * mu12 + C1) * (2.f * (sp - mu12) + C2);
                    float den = (musum + C1) * ((sq - musum) + C2);
                    acc += num * __builtin_amdgcn_rcpf(den);
                }
            }
        }
    }

    // --- block reduction + fused global reduce (atomic) ---
    #pragma unroll
    for (int off = 32; off > 0; off >>= 1)
        acc += __shfl_down(acc, off, 64);
    int wave = t >> 6;
    if ((t & 63) == 0) red[wave] = acc;
    __syncthreads();
    if (t == 0) {
        float partial = red[0] + red[1] + red[2] + red[3];
        float v = partial * scale;                 // scale = -1/count
        if (band == 0 && plane == 0) v += 1.0f;    // out = 1 - sum/count
        atomicAdd(out, v);
    }
}

extern "C" void kernel_launch(void* const* d_in, const int* in_sizes, int n_in,
                              void* d_out, int out_size, void* d_ws, size_t ws_size,
                              hipStream_t stream) {
    const float* img1   = (const float*)d_in[0];
    const float* img2   = (const float*)d_in[1];
    const float* window = (const float*)d_in[2];
    float* out = (float*)d_out;

    const int planes = 16 * 9;                     // 144
    const int bands = (Hd + OUT_R - 1) / OUT_R;    // 10 (last band 22 rows)

    hipMemsetAsync(out, 0, sizeof(float), stream);

    const float scale = -(float)(1.0 / ((double)planes * Hd * Wd));
    dim3 grid(bands, planes);
    ssim_pair_kernel<<<grid, BLOCK, 0, stream>>>(img1, img2, window, out, scale);
}